// Round 2
// baseline (447.304 us; speedup 1.0000x reference)
//
#include <hip/hip_runtime.h>

#define B_DIM 32
#define T_DIM 512
#define D_DIM 256
#define U_DIM 1024

// softsign via fast approx reciprocal (~1e-5 rel err, far below the 2% threshold)
__device__ __forceinline__ float ssign(float z) {
    return z * __builtin_amdgcn_rcpf(1.0f + __builtin_fabsf(z));
}

// Big GEMM: out[bt][u] = sum_d Xts[bt][d] * Wd[d][u]  (all f32).
// Block: 256 threads = one 256-wide u-tile; 16 bt rows per block.
// X tile staged in LDS (reads are same-address broadcasts -> conflict-free).
// W rows streamed (coalesced across u; W is 1MB -> L2 resident).
__global__ __launch_bounds__(256) void gemm_xw(const float* __restrict__ Xts,
                                               const float* __restrict__ Wd,
                                               float* __restrict__ out) {
    __shared__ float xs[16 * D_DIM];  // 16KB
    const int tid = threadIdx.x;
    const int bt0 = blockIdx.y * 16;
    const int u = blockIdx.x * 256 + tid;

    // stage 16 rows of X (4096 f32) via float4
    const float4* src4 = (const float4*)(Xts + (size_t)bt0 * D_DIM);
    float4* xs4 = (float4*)xs;
    #pragma unroll
    for (int i = 0; i < 4; ++i) xs4[tid + 256 * i] = src4[tid + 256 * i];
    __syncthreads();

    float acc[16];
    #pragma unroll
    for (int r = 0; r < 16; ++r) acc[r] = 0.0f;

    const float* wp = Wd + u;
    for (int d0 = 0; d0 < D_DIM; d0 += 4) {
        const float w0 = wp[(size_t)(d0 + 0) * U_DIM];
        const float w1 = wp[(size_t)(d0 + 1) * U_DIM];
        const float w2 = wp[(size_t)(d0 + 2) * U_DIM];
        const float w3 = wp[(size_t)(d0 + 3) * U_DIM];
        #pragma unroll
        for (int r = 0; r < 16; ++r) {
            const float4 xv = *(const float4*)&xs[r * D_DIM + d0];
            acc[r] = fmaf(xv.x, w0, acc[r]);
            acc[r] = fmaf(xv.y, w1, acc[r]);
            acc[r] = fmaf(xv.z, w2, acc[r]);
            acc[r] = fmaf(xv.w, w3, acc[r]);
        }
    }

    #pragma unroll
    for (int r = 0; r < 16; ++r)
        out[(size_t)(bt0 + r) * U_DIM + u] = acc[r];
}

// Scan: one thread per (b,u). Computes H0-pre and drive dots itself (trivial),
// then h_t = softsign(h_{t-1} + drive + XW[b,t,u]) sequentially, overwriting
// d_out in place. 8-deep register prefetch ring hides load latency
// (only 512 waves exist here -> ILP must cover what TLP can't).
__global__ __launch_bounds__(256) void scan_k(const float* __restrict__ Xv,
                                              const float* __restrict__ A0,
                                              const float* __restrict__ b0,
                                              const float* __restrict__ As,
                                              const float* __restrict__ bs,
                                              const float* __restrict__ bd,
                                              float* __restrict__ out) {
    __shared__ float xv[D_DIM];
    const int tid = threadIdx.x;
    const int b = blockIdx.y;
    const int u = blockIdx.x * 256 + tid;

    xv[tid] = Xv[(size_t)b * D_DIM + tid];
    __syncthreads();

    float a0 = 0.0f, asum = 0.0f;
    #pragma unroll 4
    for (int d = 0; d < D_DIM; ++d) {
        const float x = xv[d];
        a0   = fmaf(x, A0[(size_t)d * U_DIM + u], a0);
        asum = fmaf(x, As[(size_t)d * U_DIM + u], asum);
    }
    a0 += b0[u];
    const float drive = asum + bs[u] + bd[u];

    float h = ssign(a0);  // H0

    float* po = out + (size_t)b * T_DIM * U_DIM + u;

    float buf[8];
    #pragma unroll
    for (int i = 0; i < 8; ++i) buf[i] = po[(size_t)i * U_DIM];

    for (int t = 0; t < T_DIM; t += 8) {
        #pragma unroll
        for (int i = 0; i < 8; ++i) {
            const float x = buf[i];
            const int tn = t + i + 8;
            if (tn < T_DIM) buf[i] = po[(size_t)tn * U_DIM];
            h = ssign(h + drive + x);
            po[(size_t)(t + i) * U_DIM] = h;
        }
    }
}

extern "C" void kernel_launch(void* const* d_in, const int* in_sizes, int n_in,
                              void* d_out, int out_size, void* d_ws, size_t ws_size,
                              hipStream_t stream) {
    const float* Xv  = (const float*)d_in[0];
    const float* Xts = (const float*)d_in[1];
    const float* A0  = (const float*)d_in[2];
    const float* b0  = (const float*)d_in[3];
    const float* As  = (const float*)d_in[4];
    const float* bs  = (const float*)d_in[5];
    const float* Wd  = (const float*)d_in[6];
    const float* bd  = (const float*)d_in[7];
    float* out = (float*)d_out;

    dim3 g1(U_DIM / 256, (B_DIM * T_DIM) / 16);
    gemm_xw<<<g1, dim3(256), 0, stream>>>(Xts, Wd, out);

    dim3 g2(U_DIM / 256, B_DIM);
    scan_k<<<g2, dim3(256), 0, stream>>>(Xv, A0, b0, As, bs, bd, out);
}

// Round 3
// 165.018 us; speedup vs baseline: 2.7106x; 2.7106x over previous
//
#include <hip/hip_runtime.h>

#define B_DIM 32
#define T_DIM 512
#define D_DIM 256
#define U_DIM 1024
#define M_DIM (B_DIM * T_DIM)  // 16384

typedef __bf16 bf16_t;
typedef bf16_t bf16x8 __attribute__((ext_vector_type(8)));
typedef float f32x4 __attribute__((ext_vector_type(4)));

__device__ __forceinline__ float ssign(float z) {
    return z * __builtin_amdgcn_rcpf(1.0f + __builtin_fabsf(z));
}

// ---------------- W transpose+cast: Wd f32 [K=256][N=1024] -> Wt bf16 [N][K] ----------
__global__ __launch_bounds__(256) void transpose_w(const float* __restrict__ Wd,
                                                   bf16_t* __restrict__ Wt) {
    __shared__ float tile[64][65];
    const int tx = threadIdx.x & 63;
    const int ty = threadIdx.x >> 6;  // 0..3
    const int n0 = blockIdx.x * 64;
    const int k0 = blockIdx.y * 64;
    #pragma unroll
    for (int rr = 0; rr < 16; ++rr) {
        const int kk = ty * 16 + rr;
        tile[kk][tx] = Wd[(size_t)(k0 + kk) * U_DIM + n0 + tx];
    }
    __syncthreads();
    #pragma unroll
    for (int rr = 0; rr < 16; ++rr) {
        const int nn = ty * 16 + rr;
        Wt[(size_t)(n0 + nn) * D_DIM + k0 + tx] = (bf16_t)tile[tx][nn];
    }
}

// ---------------- MFMA GEMM: XW[bt][u] = sum_k X[bt][k] * W[k][u] ---------------------
// 128x128 tile, BK=32, 4 waves each 64x64 (4x4 grid of 16x16x32 mfma).
// LDS row stride 40 shorts (80B): 16B-aligned b128 frag reads, 2-way banks (free).
#define LDS_STRIDE 40
__global__ __launch_bounds__(256) void gemm_mfma(const float* __restrict__ X,
                                                 const bf16_t* __restrict__ Wt,
                                                 float* __restrict__ XW) {
    __shared__ bf16_t sA[128 * LDS_STRIDE];
    __shared__ bf16_t sB[128 * LDS_STRIDE];
    const int t = threadIdx.x;
    const int bt0 = blockIdx.y * 128;
    const int n0 = blockIdx.x * 128;
    const int w = t >> 6, lane = t & 63;
    const int lm = lane & 15, q = lane >> 4;
    const int mb = (w & 1) * 64, nb = (w >> 1) * 64;

    const int rS = t >> 1;       // staging row 0..127
    const int hS = t & 1;        // k-half (16 elems)
    const float*  gA = X + (size_t)(bt0 + rS) * D_DIM + hS * 16;
    const short*  gB = (const short*)Wt + (size_t)(n0 + rS) * D_DIM + hS * 16;
    bf16_t* wA = &sA[rS * LDS_STRIDE + hS * 16];
    short*  wB = (short*)&sB[rS * LDS_STRIDE + hS * 16];

    f32x4 acc[4][4];
    #pragma unroll
    for (int i = 0; i < 4; ++i)
        #pragma unroll
        for (int j = 0; j < 4; ++j) acc[i][j] = (f32x4){0.f, 0.f, 0.f, 0.f};

    for (int kt = 0; kt < 8; ++kt) {
        // stage A (f32 -> bf16)
        const float4 a0 = *(const float4*)(gA + kt * 32 + 0);
        const float4 a1 = *(const float4*)(gA + kt * 32 + 4);
        const float4 a2 = *(const float4*)(gA + kt * 32 + 8);
        const float4 a3 = *(const float4*)(gA + kt * 32 + 12);
        bf16x8 p0, p1;
        p0[0]=(bf16_t)a0.x; p0[1]=(bf16_t)a0.y; p0[2]=(bf16_t)a0.z; p0[3]=(bf16_t)a0.w;
        p0[4]=(bf16_t)a1.x; p0[5]=(bf16_t)a1.y; p0[6]=(bf16_t)a1.z; p0[7]=(bf16_t)a1.w;
        p1[0]=(bf16_t)a2.x; p1[1]=(bf16_t)a2.y; p1[2]=(bf16_t)a2.z; p1[3]=(bf16_t)a2.w;
        p1[4]=(bf16_t)a3.x; p1[5]=(bf16_t)a3.y; p1[6]=(bf16_t)a3.z; p1[7]=(bf16_t)a3.w;
        *(bf16x8*)(wA + 0) = p0;
        *(bf16x8*)(wA + 8) = p1;
        // stage B (already bf16, straight copy)
        const int4 b0 = *(const int4*)(gB + kt * 32);
        const int4 b1 = *(const int4*)(gB + kt * 32 + 8);
        *(int4*)(wB + 0) = b0;
        *(int4*)(wB + 8) = b1;
        __syncthreads();

        bf16x8 aF[4], bF[4];
        #pragma unroll
        for (int mi = 0; mi < 4; ++mi)
            aF[mi] = *(const bf16x8*)&sA[(mb + mi * 16 + lm) * LDS_STRIDE + q * 8];
        #pragma unroll
        for (int ni = 0; ni < 4; ++ni)
            bF[ni] = *(const bf16x8*)&sB[(nb + ni * 16 + lm) * LDS_STRIDE + q * 8];
        #pragma unroll
        for (int mi = 0; mi < 4; ++mi)
            #pragma unroll
            for (int ni = 0; ni < 4; ++ni)
                acc[mi][ni] = __builtin_amdgcn_mfma_f32_16x16x32_bf16(aF[mi], bF[ni], acc[mi][ni], 0, 0, 0);
        __syncthreads();
    }

    // epilogue: C/D layout col=lane&15, row=quad*4+reg
    #pragma unroll
    for (int mi = 0; mi < 4; ++mi) {
        #pragma unroll
        for (int ni = 0; ni < 4; ++ni) {
            const int col = n0 + nb + ni * 16 + lm;
            #pragma unroll
            for (int r = 0; r < 4; ++r) {
                const int row = bt0 + mb + mi * 16 + q * 4 + r;
                XW[(size_t)row * U_DIM + col] = acc[mi][ni][r];
            }
        }
    }
}

// ---------------- Scan: h_t = softsign(h_{t-1} + drive + XW[b,t,u]) -------------------
// 64-thread blocks (1 wave) x 256 blocks -> 1 wave/CU; float2 per thread;
// statically double-buffered 16-deep prefetch (2MB in flight machine-wide).
__global__ __launch_bounds__(64) void scan2(const float* __restrict__ Xv,
                                            const float* __restrict__ A0,
                                            const float* __restrict__ b0,
                                            const float* __restrict__ As,
                                            const float* __restrict__ bs,
                                            const float* __restrict__ bd,
                                            const float* __restrict__ xw,
                                            float* __restrict__ out) {
    __shared__ float xv[D_DIM];
    const int tid = threadIdx.x;
    const int g = blockIdx.x * 64 + tid;
    const int b = g >> 9;
    const int u = (g & 511) * 2;

    ((float4*)xv)[tid] = ((const float4*)(Xv + (size_t)b * D_DIM))[tid];
    __syncthreads();

    float a0x = 0.f, a0y = 0.f, asx = 0.f, asy = 0.f;
    #pragma unroll 8
    for (int d = 0; d < D_DIM; ++d) {
        const float x = xv[d];
        const float2 a = *(const float2*)&A0[(size_t)d * U_DIM + u];
        const float2 s = *(const float2*)&As[(size_t)d * U_DIM + u];
        a0x = fmaf(x, a.x, a0x); a0y = fmaf(x, a.y, a0y);
        asx = fmaf(x, s.x, asx); asy = fmaf(x, s.y, asy);
    }
    const float2 b0v = *(const float2*)&b0[u];
    const float2 bsv = *(const float2*)&bs[u];
    const float2 bdv = *(const float2*)&bd[u];
    const float dx = asx + bsv.x + bdv.x;
    const float dy = asy + bsv.y + bdv.y;
    float hx = ssign(a0x + b0v.x);
    float hy = ssign(a0y + b0v.y);

    const float* pi = xw + (size_t)b * T_DIM * U_DIM + u;
    float* po = out + (size_t)b * T_DIM * U_DIM + u;

    float2 rA[16], rB[16];
    #pragma unroll
    for (int i = 0; i < 16; ++i) rA[i] = *(const float2*)(pi + (size_t)i * U_DIM);

    for (int t0 = 0; t0 < T_DIM; t0 += 32) {
        #pragma unroll
        for (int i = 0; i < 16; ++i) rB[i] = *(const float2*)(pi + (size_t)(t0 + 16 + i) * U_DIM);
        #pragma unroll
        for (int i = 0; i < 16; ++i) {
            const float2 x = rA[i];
            hx = ssign(hx + dx + x.x);
            hy = ssign(hy + dy + x.y);
            *(float2*)(po + (size_t)(t0 + i) * U_DIM) = make_float2(hx, hy);
        }
        if (t0 + 32 < T_DIM) {
            #pragma unroll
            for (int i = 0; i < 16; ++i) rA[i] = *(const float2*)(pi + (size_t)(t0 + 32 + i) * U_DIM);
        }
        #pragma unroll
        for (int i = 0; i < 16; ++i) {
            const float2 x = rB[i];
            hx = ssign(hx + dx + x.x);
            hy = ssign(hy + dy + x.y);
            *(float2*)(po + (size_t)(t0 + 16 + i) * U_DIM) = make_float2(hx, hy);
        }
    }
}

// ---------------- Fallback (tiny ws): round-2 kernels --------------------------------
__global__ __launch_bounds__(256) void gemm_xw_f32(const float* __restrict__ Xts,
                                                   const float* __restrict__ Wd,
                                                   float* __restrict__ out) {
    __shared__ float xs[16 * D_DIM];
    const int tid = threadIdx.x;
    const int bt0 = blockIdx.y * 16;
    const int u = blockIdx.x * 256 + tid;
    const float4* src4 = (const float4*)(Xts + (size_t)bt0 * D_DIM);
    float4* xs4 = (float4*)xs;
    #pragma unroll
    for (int i = 0; i < 4; ++i) xs4[tid + 256 * i] = src4[tid + 256 * i];
    __syncthreads();
    float acc[16];
    #pragma unroll
    for (int r = 0; r < 16; ++r) acc[r] = 0.0f;
    const float* wp = Wd + u;
    for (int d0 = 0; d0 < D_DIM; d0 += 4) {
        const float w0 = wp[(size_t)(d0 + 0) * U_DIM];
        const float w1 = wp[(size_t)(d0 + 1) * U_DIM];
        const float w2 = wp[(size_t)(d0 + 2) * U_DIM];
        const float w3 = wp[(size_t)(d0 + 3) * U_DIM];
        #pragma unroll
        for (int r = 0; r < 16; ++r) {
            const float4 xvv = *(const float4*)&xs[r * D_DIM + d0];
            acc[r] = fmaf(xvv.x, w0, acc[r]);
            acc[r] = fmaf(xvv.y, w1, acc[r]);
            acc[r] = fmaf(xvv.z, w2, acc[r]);
            acc[r] = fmaf(xvv.w, w3, acc[r]);
        }
    }
    #pragma unroll
    for (int r = 0; r < 16; ++r)
        out[(size_t)(bt0 + r) * U_DIM + u] = acc[r];
}

__global__ __launch_bounds__(256) void scan_old(const float* __restrict__ Xv,
                                                const float* __restrict__ A0,
                                                const float* __restrict__ b0,
                                                const float* __restrict__ As,
                                                const float* __restrict__ bs,
                                                const float* __restrict__ bd,
                                                float* __restrict__ out) {
    __shared__ float xv[D_DIM];
    const int tid = threadIdx.x;
    const int b = blockIdx.y;
    const int u = blockIdx.x * 256 + tid;
    xv[tid] = Xv[(size_t)b * D_DIM + tid];
    __syncthreads();
    float a0 = 0.0f, asum = 0.0f;
    #pragma unroll 4
    for (int d = 0; d < D_DIM; ++d) {
        const float x = xv[d];
        a0   = fmaf(x, A0[(size_t)d * U_DIM + u], a0);
        asum = fmaf(x, As[(size_t)d * U_DIM + u], asum);
    }
    a0 += b0[u];
    const float drive = asum + bs[u] + bd[u];
    float h = ssign(a0);
    float* po = out + (size_t)b * T_DIM * U_DIM + u;
    float buf[8];
    #pragma unroll
    for (int i = 0; i < 8; ++i) buf[i] = po[(size_t)i * U_DIM];
    for (int t = 0; t < T_DIM; t += 8) {
        #pragma unroll
        for (int i = 0; i < 8; ++i) {
            const float x = buf[i];
            const int tn = t + i + 8;
            if (tn < T_DIM) buf[i] = po[(size_t)tn * U_DIM];
            h = ssign(h + drive + x);
            po[(size_t)(t + i) * U_DIM] = h;
        }
    }
}

extern "C" void kernel_launch(void* const* d_in, const int* in_sizes, int n_in,
                              void* d_out, int out_size, void* d_ws, size_t ws_size,
                              hipStream_t stream) {
    const float* Xv  = (const float*)d_in[0];
    const float* Xts = (const float*)d_in[1];
    const float* A0  = (const float*)d_in[2];
    const float* b0  = (const float*)d_in[3];
    const float* As  = (const float*)d_in[4];
    const float* bs  = (const float*)d_in[5];
    const float* Wd  = (const float*)d_in[6];
    const float* bd  = (const float*)d_in[7];
    float* out = (float*)d_out;

    const size_t WT_BYTES = (size_t)U_DIM * D_DIM * sizeof(short);   // 512 KB
    const size_t XW_OFF   = 1u << 20;                                // 1 MB
    const size_t XW_BYTES = (size_t)M_DIM * U_DIM * sizeof(float);   // 64 MB

    if (ws_size >= WT_BYTES) {
        bf16_t* Wt = (bf16_t*)d_ws;
        transpose_w<<<dim3(U_DIM / 64, D_DIM / 64), dim3(256), 0, stream>>>(Wd, Wt);

        float* xwbuf = (ws_size >= XW_OFF + XW_BYTES) ? (float*)((char*)d_ws + XW_OFF) : out;
        gemm_mfma<<<dim3(U_DIM / 128, M_DIM / 128), dim3(256), 0, stream>>>(Xts, Wt, xwbuf);
        scan2<<<dim3(256), dim3(64), 0, stream>>>(Xv, A0, b0, As, bs, bd, xwbuf, out);
    } else {
        gemm_xw_f32<<<dim3(U_DIM / 256, M_DIM / 16), dim3(256), 0, stream>>>(Xts, Wd, out);
        scan_old<<<dim3(U_DIM / 256, B_DIM), dim3(256), 0, stream>>>(Xv, A0, b0, As, bs, bd, out);
    }
}

// Round 4
// 153.873 us; speedup vs baseline: 2.9070x; 1.0724x over previous
//
#include <hip/hip_runtime.h>

#define B_DIM 32
#define T_DIM 512
#define D_DIM 256
#define U_DIM 1024
#define M_DIM (B_DIM * T_DIM)  // 16384

typedef __bf16 bf16_t;
typedef bf16_t bf16x8 __attribute__((ext_vector_type(8)));
typedef float f32x4 __attribute__((ext_vector_type(4)));

__device__ __forceinline__ float ssign(float z) {
    return z * __builtin_amdgcn_rcpf(1.0f + __builtin_fabsf(z));
}

// async global->LDS, 16B per lane. LDS dest is wave-uniform-base + lane*16;
// we pass the per-lane pointer which equals exactly that.
__device__ __forceinline__ void gl_lds16(const void* g, void* l) {
    __builtin_amdgcn_global_load_lds(
        (const __attribute__((address_space(1))) void*)g,
        (__attribute__((address_space(3))) void*)l, 16, 0, 0);
}

// ---------------- X cast: f32 [M][K] -> bf16 [M][K] ----------------------------------
__global__ __launch_bounds__(256) void xcast(const float* __restrict__ X,
                                             bf16_t* __restrict__ Xb) {
    const int i = (blockIdx.x * 256 + threadIdx.x) * 8;
    const float4 a = *(const float4*)(X + i);
    const float4 b = *(const float4*)(X + i + 4);
    bf16x8 p;
    p[0]=(bf16_t)a.x; p[1]=(bf16_t)a.y; p[2]=(bf16_t)a.z; p[3]=(bf16_t)a.w;
    p[4]=(bf16_t)b.x; p[5]=(bf16_t)b.y; p[6]=(bf16_t)b.z; p[7]=(bf16_t)b.w;
    *(bf16x8*)(Xb + i) = p;
}

// ---------------- W transpose+cast: Wd f32 [K=256][N=1024] -> Wt bf16 [N][K] ----------
__global__ __launch_bounds__(256) void transpose_w(const float* __restrict__ Wd,
                                                   bf16_t* __restrict__ Wt) {
    __shared__ float tile[64][65];
    const int tx = threadIdx.x & 63;
    const int ty = threadIdx.x >> 6;  // 0..3
    const int n0 = blockIdx.x * 64;
    const int k0 = blockIdx.y * 64;
    #pragma unroll
    for (int rr = 0; rr < 16; ++rr) {
        const int kk = ty * 16 + rr;
        tile[kk][tx] = Wd[(size_t)(k0 + kk) * U_DIM + n0 + tx];
    }
    __syncthreads();
    #pragma unroll
    for (int rr = 0; rr < 16; ++rr) {
        const int nn = ty * 16 + rr;
        Wt[(size_t)(n0 + nn) * D_DIM + k0 + tx] = (bf16_t)tile[tx][nn];
    }
}

// ---------------- MFMA GEMM (m97-style): XW = Xb @ Wt^T ------------------------------
// 128x128 tile, BK=32, 4 waves each 64x64 (4x4 of 16x16x32 mfma).
// Both operands k-major bf16; staging via global_load_lds width 16; LDS rows
// unpadded (64B stride, 2-way bank aliasing = free).
__global__ __launch_bounds__(256) void gemm_mfma2(const bf16_t* __restrict__ Xb,
                                                  const bf16_t* __restrict__ Wt,
                                                  float* __restrict__ XW) {
    __shared__ bf16_t sA[128 * 32];  // 8KB
    __shared__ bf16_t sB[128 * 32];  // 8KB
    const int t = threadIdx.x;
    const int w = t >> 6, lane = t & 63;
    const int bt0 = blockIdx.y * 128;
    const int n0 = blockIdx.x * 128;
    const int lm = lane & 15, q = lane >> 4;
    const int mb = (w & 1) * 64, nb = (w >> 1) * 64;

    f32x4 acc[4][4];
    #pragma unroll
    for (int i = 0; i < 4; ++i)
        #pragma unroll
        for (int j = 0; j < 4; ++j) acc[i][j] = (f32x4){0.f, 0.f, 0.f, 0.f};

    for (int kt = 0; kt < 8; ++kt) {
        const int k0 = kt * 32;
        #pragma unroll
        for (int j = 0; j < 2; ++j) {
            const int c = w * 128 + j * 64 + lane;   // 16B-chunk index 0..511
            const int row = c >> 2, kc = c & 3;
            gl_lds16(Xb + (size_t)(bt0 + row) * D_DIM + k0 + kc * 8, &sA[c * 8]);
            gl_lds16(Wt + (size_t)(n0 + row) * D_DIM + k0 + kc * 8, &sB[c * 8]);
        }
        __syncthreads();

        bf16x8 aF[4], bF[4];
        #pragma unroll
        for (int mi = 0; mi < 4; ++mi)
            aF[mi] = *(const bf16x8*)&sA[(mb + mi * 16 + lm) * 32 + q * 8];
        #pragma unroll
        for (int ni = 0; ni < 4; ++ni)
            bF[ni] = *(const bf16x8*)&sB[(nb + ni * 16 + lm) * 32 + q * 8];
        #pragma unroll
        for (int mi = 0; mi < 4; ++mi)
            #pragma unroll
            for (int ni = 0; ni < 4; ++ni)
                acc[mi][ni] = __builtin_amdgcn_mfma_f32_16x16x32_bf16(aF[mi], bF[ni], acc[mi][ni], 0, 0, 0);
        __syncthreads();
    }

    #pragma unroll
    for (int mi = 0; mi < 4; ++mi) {
        #pragma unroll
        for (int ni = 0; ni < 4; ++ni) {
            const int col = n0 + nb + ni * 16 + lm;
            #pragma unroll
            for (int r = 0; r < 4; ++r) {
                const int row = bt0 + mb + mi * 16 + q * 4 + r;
                XW[(size_t)row * U_DIM + col] = acc[mi][ni][r];
            }
        }
    }
}

// ---------------- Scan, 32-deep ping-pong prefetch (4MB in flight) -------------------
__global__ __launch_bounds__(64) void scan3(const float* __restrict__ Xv,
                                            const float* __restrict__ A0,
                                            const float* __restrict__ b0,
                                            const float* __restrict__ As,
                                            const float* __restrict__ bs,
                                            const float* __restrict__ bd,
                                            const float* __restrict__ xw,
                                            float* __restrict__ out) {
    __shared__ float xv[D_DIM];
    const int tid = threadIdx.x;
    const int g = blockIdx.x * 64 + tid;
    const int b = g >> 9;
    const int u = (g & 511) * 2;

    ((float4*)xv)[tid] = ((const float4*)(Xv + (size_t)b * D_DIM))[tid];
    __syncthreads();

    float a0x = 0.f, a0y = 0.f, asx = 0.f, asy = 0.f;
    #pragma unroll 8
    for (int d = 0; d < D_DIM; ++d) {
        const float x = xv[d];
        const float2 a = *(const float2*)&A0[(size_t)d * U_DIM + u];
        const float2 s = *(const float2*)&As[(size_t)d * U_DIM + u];
        a0x = fmaf(x, a.x, a0x); a0y = fmaf(x, a.y, a0y);
        asx = fmaf(x, s.x, asx); asy = fmaf(x, s.y, asy);
    }
    const float2 b0v = *(const float2*)&b0[u];
    const float2 bsv = *(const float2*)&bs[u];
    const float2 bdv = *(const float2*)&bd[u];
    const float dx = asx + bsv.x + bdv.x;
    const float dy = asy + bsv.y + bdv.y;
    float hx = ssign(a0x + b0v.x);
    float hy = ssign(a0y + b0v.y);

    const float* pi = xw + (size_t)b * T_DIM * U_DIM + u;
    float* po = out + (size_t)b * T_DIM * U_DIM + u;

    float2 rA[32], rB[32];
    #pragma unroll
    for (int i = 0; i < 32; ++i) rA[i] = *(const float2*)(pi + (size_t)i * U_DIM);

    for (int t0 = 0; t0 < T_DIM; t0 += 64) {
        #pragma unroll
        for (int i = 0; i < 32; ++i) rB[i] = *(const float2*)(pi + (size_t)(t0 + 32 + i) * U_DIM);
        #pragma unroll
        for (int i = 0; i < 32; ++i) {
            hx = ssign(hx + dx + rA[i].x);
            hy = ssign(hy + dy + rA[i].y);
            *(float2*)(po + (size_t)(t0 + i) * U_DIM) = make_float2(hx, hy);
        }
        if (t0 + 64 < T_DIM) {
            #pragma unroll
            for (int i = 0; i < 32; ++i) rA[i] = *(const float2*)(pi + (size_t)(t0 + 64 + i) * U_DIM);
        }
        #pragma unroll
        for (int i = 0; i < 32; ++i) {
            hx = ssign(hx + dx + rB[i].x);
            hy = ssign(hy + dy + rB[i].y);
            *(float2*)(po + (size_t)(t0 + 32 + i) * U_DIM) = make_float2(hx, hy);
        }
    }
}

// ---------------- Tier-B fallback: round-3 kernels (proven) --------------------------
#define LDS_STRIDE 40
__global__ __launch_bounds__(256) void gemm_mfma(const float* __restrict__ X,
                                                 const bf16_t* __restrict__ Wt,
                                                 float* __restrict__ XW) {
    __shared__ bf16_t sA[128 * LDS_STRIDE];
    __shared__ bf16_t sB[128 * LDS_STRIDE];
    const int t = threadIdx.x;
    const int bt0 = blockIdx.y * 128;
    const int n0 = blockIdx.x * 128;
    const int w = t >> 6, lane = t & 63;
    const int lm = lane & 15, q = lane >> 4;
    const int mb = (w & 1) * 64, nb = (w >> 1) * 64;
    const int rS = t >> 1;
    const int hS = t & 1;
    const float*  gA = X + (size_t)(bt0 + rS) * D_DIM + hS * 16;
    const short*  gB = (const short*)Wt + (size_t)(n0 + rS) * D_DIM + hS * 16;
    bf16_t* wA = &sA[rS * LDS_STRIDE + hS * 16];
    short*  wB = (short*)&sB[rS * LDS_STRIDE + hS * 16];
    f32x4 acc[4][4];
    #pragma unroll
    for (int i = 0; i < 4; ++i)
        #pragma unroll
        for (int j = 0; j < 4; ++j) acc[i][j] = (f32x4){0.f, 0.f, 0.f, 0.f};
    for (int kt = 0; kt < 8; ++kt) {
        const float4 a0 = *(const float4*)(gA + kt * 32 + 0);
        const float4 a1 = *(const float4*)(gA + kt * 32 + 4);
        const float4 a2 = *(const float4*)(gA + kt * 32 + 8);
        const float4 a3 = *(const float4*)(gA + kt * 32 + 12);
        bf16x8 p0, p1;
        p0[0]=(bf16_t)a0.x; p0[1]=(bf16_t)a0.y; p0[2]=(bf16_t)a0.z; p0[3]=(bf16_t)a0.w;
        p0[4]=(bf16_t)a1.x; p0[5]=(bf16_t)a1.y; p0[6]=(bf16_t)a1.z; p0[7]=(bf16_t)a1.w;
        p1[0]=(bf16_t)a2.x; p1[1]=(bf16_t)a2.y; p1[2]=(bf16_t)a2.z; p1[3]=(bf16_t)a2.w;
        p1[4]=(bf16_t)a3.x; p1[5]=(bf16_t)a3.y; p1[6]=(bf16_t)a3.z; p1[7]=(bf16_t)a3.w;
        *(bf16x8*)(wA + 0) = p0;
        *(bf16x8*)(wA + 8) = p1;
        const int4 b0 = *(const int4*)(gB + kt * 32);
        const int4 b1 = *(const int4*)(gB + kt * 32 + 8);
        *(int4*)(wB + 0) = b0;
        *(int4*)(wB + 8) = b1;
        __syncthreads();
        bf16x8 aF[4], bF[4];
        #pragma unroll
        for (int mi = 0; mi < 4; ++mi)
            aF[mi] = *(const bf16x8*)&sA[(mb + mi * 16 + lm) * LDS_STRIDE + q * 8];
        #pragma unroll
        for (int ni = 0; ni < 4; ++ni)
            bF[ni] = *(const bf16x8*)&sB[(nb + ni * 16 + lm) * LDS_STRIDE + q * 8];
        #pragma unroll
        for (int mi = 0; mi < 4; ++mi)
            #pragma unroll
            for (int ni = 0; ni < 4; ++ni)
                acc[mi][ni] = __builtin_amdgcn_mfma_f32_16x16x32_bf16(aF[mi], bF[ni], acc[mi][ni], 0, 0, 0);
        __syncthreads();
    }
    #pragma unroll
    for (int mi = 0; mi < 4; ++mi) {
        #pragma unroll
        for (int ni = 0; ni < 4; ++ni) {
            const int col = n0 + nb + ni * 16 + lm;
            #pragma unroll
            for (int r = 0; r < 4; ++r) {
                const int row = bt0 + mb + mi * 16 + q * 4 + r;
                XW[(size_t)row * U_DIM + col] = acc[mi][ni][r];
            }
        }
    }
}

__global__ __launch_bounds__(64) void scan2(const float* __restrict__ Xv,
                                            const float* __restrict__ A0,
                                            const float* __restrict__ b0,
                                            const float* __restrict__ As,
                                            const float* __restrict__ bs,
                                            const float* __restrict__ bd,
                                            const float* __restrict__ xw,
                                            float* __restrict__ out) {
    __shared__ float xv[D_DIM];
    const int tid = threadIdx.x;
    const int g = blockIdx.x * 64 + tid;
    const int b = g >> 9;
    const int u = (g & 511) * 2;
    ((float4*)xv)[tid] = ((const float4*)(Xv + (size_t)b * D_DIM))[tid];
    __syncthreads();
    float a0x = 0.f, a0y = 0.f, asx = 0.f, asy = 0.f;
    #pragma unroll 8
    for (int d = 0; d < D_DIM; ++d) {
        const float x = xv[d];
        const float2 a = *(const float2*)&A0[(size_t)d * U_DIM + u];
        const float2 s = *(const float2*)&As[(size_t)d * U_DIM + u];
        a0x = fmaf(x, a.x, a0x); a0y = fmaf(x, a.y, a0y);
        asx = fmaf(x, s.x, asx); asy = fmaf(x, s.y, asy);
    }
    const float2 b0v = *(const float2*)&b0[u];
    const float2 bsv = *(const float2*)&bs[u];
    const float2 bdv = *(const float2*)&bd[u];
    const float dx = asx + bsv.x + bdv.x;
    const float dy = asy + bsv.y + bdv.y;
    float hx = ssign(a0x + b0v.x);
    float hy = ssign(a0y + b0v.y);
    const float* pi = xw + (size_t)b * T_DIM * U_DIM + u;
    float* po = out + (size_t)b * T_DIM * U_DIM + u;
    float2 rA[16], rB[16];
    #pragma unroll
    for (int i = 0; i < 16; ++i) rA[i] = *(const float2*)(pi + (size_t)i * U_DIM);
    for (int t0 = 0; t0 < T_DIM; t0 += 32) {
        #pragma unroll
        for (int i = 0; i < 16; ++i) rB[i] = *(const float2*)(pi + (size_t)(t0 + 16 + i) * U_DIM);
        #pragma unroll
        for (int i = 0; i < 16; ++i) {
            hx = ssign(hx + dx + rA[i].x);
            hy = ssign(hy + dy + rA[i].y);
            *(float2*)(po + (size_t)(t0 + i) * U_DIM) = make_float2(hx, hy);
        }
        if (t0 + 32 < T_DIM) {
            #pragma unroll
            for (int i = 0; i < 16; ++i) rA[i] = *(const float2*)(pi + (size_t)(t0 + 32 + i) * U_DIM);
        }
        #pragma unroll
        for (int i = 0; i < 16; ++i) {
            hx = ssign(hx + dx + rB[i].x);
            hy = ssign(hy + dy + rB[i].y);
            *(float2*)(po + (size_t)(t0 + 16 + i) * U_DIM) = make_float2(hx, hy);
        }
    }
}

// ---------------- Tier-C fallback (tiny ws): f32 path --------------------------------
__global__ __launch_bounds__(256) void gemm_xw_f32(const float* __restrict__ Xts,
                                                   const float* __restrict__ Wd,
                                                   float* __restrict__ out) {
    __shared__ float xs[16 * D_DIM];
    const int tid = threadIdx.x;
    const int bt0 = blockIdx.y * 16;
    const int u = blockIdx.x * 256 + tid;
    const float4* src4 = (const float4*)(Xts + (size_t)bt0 * D_DIM);
    float4* xs4 = (float4*)xs;
    #pragma unroll
    for (int i = 0; i < 4; ++i) xs4[tid + 256 * i] = src4[tid + 256 * i];
    __syncthreads();
    float acc[16];
    #pragma unroll
    for (int r = 0; r < 16; ++r) acc[r] = 0.0f;
    const float* wp = Wd + u;
    for (int d0 = 0; d0 < D_DIM; d0 += 4) {
        const float w0 = wp[(size_t)(d0 + 0) * U_DIM];
        const float w1 = wp[(size_t)(d0 + 1) * U_DIM];
        const float w2 = wp[(size_t)(d0 + 2) * U_DIM];
        const float w3 = wp[(size_t)(d0 + 3) * U_DIM];
        #pragma unroll
        for (int r = 0; r < 16; ++r) {
            const float4 xvv = *(const float4*)&xs[r * D_DIM + d0];
            acc[r] = fmaf(xvv.x, w0, acc[r]);
            acc[r] = fmaf(xvv.y, w1, acc[r]);
            acc[r] = fmaf(xvv.z, w2, acc[r]);
            acc[r] = fmaf(xvv.w, w3, acc[r]);
        }
    }
    #pragma unroll
    for (int r = 0; r < 16; ++r)
        out[(size_t)(bt0 + r) * U_DIM + u] = acc[r];
}

__global__ __launch_bounds__(256) void scan_old(const float* __restrict__ Xv,
                                                const float* __restrict__ A0,
                                                const float* __restrict__ b0,
                                                const float* __restrict__ As,
                                                const float* __restrict__ bs,
                                                const float* __restrict__ bd,
                                                float* __restrict__ out) {
    __shared__ float xv[D_DIM];
    const int tid = threadIdx.x;
    const int b = blockIdx.y;
    const int u = blockIdx.x * 256 + tid;
    xv[tid] = Xv[(size_t)b * D_DIM + tid];
    __syncthreads();
    float a0 = 0.0f, asum = 0.0f;
    #pragma unroll 4
    for (int d = 0; d < D_DIM; ++d) {
        const float x = xv[d];
        a0   = fmaf(x, A0[(size_t)d * U_DIM + u], a0);
        asum = fmaf(x, As[(size_t)d * U_DIM + u], asum);
    }
    a0 += b0[u];
    const float drive = asum + bs[u] + bd[u];
    float h = ssign(a0);
    float* po = out + (size_t)b * T_DIM * U_DIM + u;
    float buf[8];
    #pragma unroll
    for (int i = 0; i < 8; ++i) buf[i] = po[(size_t)i * U_DIM];
    for (int t = 0; t < T_DIM; t += 8) {
        #pragma unroll
        for (int i = 0; i < 8; ++i) {
            const float x = buf[i];
            const int tn = t + i + 8;
            if (tn < T_DIM) buf[i] = po[(size_t)tn * U_DIM];
            h = ssign(h + drive + x);
            po[(size_t)(t + i) * U_DIM] = h;
        }
    }
}

extern "C" void kernel_launch(void* const* d_in, const int* in_sizes, int n_in,
                              void* d_out, int out_size, void* d_ws, size_t ws_size,
                              hipStream_t stream) {
    const float* Xv  = (const float*)d_in[0];
    const float* Xts = (const float*)d_in[1];
    const float* A0  = (const float*)d_in[2];
    const float* b0  = (const float*)d_in[3];
    const float* As  = (const float*)d_in[4];
    const float* bs  = (const float*)d_in[5];
    const float* Wd  = (const float*)d_in[6];
    const float* bd  = (const float*)d_in[7];
    float* out = (float*)d_out;

    // Tier-A workspace layout: Wt [0,512K) | Xb [1M,9.4M) | XW [16M,80M)
    const size_t OFF_XB = 1u << 20;
    const size_t OFF_XW = 16u << 20;
    const size_t NEED_A = OFF_XW + (size_t)M_DIM * U_DIM * sizeof(float);  // 80MB
    const size_t WT_BYTES = (size_t)U_DIM * D_DIM * sizeof(short);         // 512KB
    const size_t NEED_B = OFF_XB + (size_t)M_DIM * U_DIM * sizeof(float);  // 65MB

    if (ws_size >= NEED_A) {
        bf16_t* Wt = (bf16_t*)d_ws;
        bf16_t* Xb = (bf16_t*)((char*)d_ws + OFF_XB);
        float* xwbuf = (float*)((char*)d_ws + OFF_XW);
        transpose_w<<<dim3(U_DIM / 64, D_DIM / 64), dim3(256), 0, stream>>>(Wd, Wt);
        xcast<<<dim3(M_DIM * D_DIM / (256 * 8)), dim3(256), 0, stream>>>(Xts, Xb);
        gemm_mfma2<<<dim3(U_DIM / 128, M_DIM / 128), dim3(256), 0, stream>>>(Xb, Wt, xwbuf);
        scan3<<<dim3(256), dim3(64), 0, stream>>>(Xv, A0, b0, As, bs, bd, xwbuf, out);
    } else if (ws_size >= WT_BYTES) {
        bf16_t* Wt = (bf16_t*)d_ws;
        transpose_w<<<dim3(U_DIM / 64, D_DIM / 64), dim3(256), 0, stream>>>(Wd, Wt);
        float* xwbuf = (ws_size >= NEED_B) ? (float*)((char*)d_ws + OFF_XB) : out;
        gemm_mfma<<<dim3(U_DIM / 128, M_DIM / 128), dim3(256), 0, stream>>>(Xts, Wt, xwbuf);
        scan2<<<dim3(256), dim3(64), 0, stream>>>(Xv, A0, b0, As, bs, bd, xwbuf, out);
    } else {
        gemm_xw_f32<<<dim3(U_DIM / 256, M_DIM / 16), dim3(256), 0, stream>>>(Xts, Wd, out);
        scan_old<<<dim3(U_DIM / 256, B_DIM), dim3(256), 0, stream>>>(Xv, A0, b0, As, bs, bd, out);
    }
}

// Round 5
// 135.701 us; speedup vs baseline: 3.2962x; 1.1339x over previous
//
#include <hip/hip_runtime.h>

#define B_DIM 32
#define T_DIM 512
#define D_DIM 256
#define U_DIM 1024
#define M_DIM (B_DIM * T_DIM)  // 16384

typedef __bf16 bf16_t;
typedef bf16_t bf16x8 __attribute__((ext_vector_type(8)));
typedef float f32x4 __attribute__((ext_vector_type(4)));

__device__ __forceinline__ float ssign(float z) {
    return z * __builtin_amdgcn_rcpf(1.0f + __builtin_fabsf(z));
}

// ---------------- X cast: f32 [M][K] -> bf16 [M][K] ----------------------------------
__global__ __launch_bounds__(256) void xcast(const float* __restrict__ X,
                                             bf16_t* __restrict__ Xb) {
    const int i = (blockIdx.x * 256 + threadIdx.x) * 8;
    const float4 a = *(const float4*)(X + i);
    const float4 b = *(const float4*)(X + i + 4);
    bf16x8 p;
    p[0]=(bf16_t)a.x; p[1]=(bf16_t)a.y; p[2]=(bf16_t)a.z; p[3]=(bf16_t)a.w;
    p[4]=(bf16_t)b.x; p[5]=(bf16_t)b.y; p[6]=(bf16_t)b.z; p[7]=(bf16_t)b.w;
    *(bf16x8*)(Xb + i) = p;
}

// ---------------- W transpose+cast: Wd f32 [K=256][N=1024] -> Wt bf16 [N][K] ----------
__global__ __launch_bounds__(256) void transpose_w(const float* __restrict__ Wd,
                                                   bf16_t* __restrict__ Wt) {
    __shared__ float tile[64][65];
    const int tx = threadIdx.x & 63;
    const int ty = threadIdx.x >> 6;  // 0..3
    const int n0 = blockIdx.x * 64;
    const int k0 = blockIdx.y * 64;
    #pragma unroll
    for (int rr = 0; rr < 16; ++rr) {
        const int kk = ty * 16 + rr;
        tile[kk][tx] = Wd[(size_t)(k0 + kk) * U_DIM + n0 + tx];
    }
    __syncthreads();
    #pragma unroll
    for (int rr = 0; rr < 16; ++rr) {
        const int nn = ty * 16 + rr;
        Wt[(size_t)(n0 + nn) * D_DIM + k0 + tx] = (bf16_t)tile[tx][nn];
    }
}

// ---------------- Fused GEMM+scan -----------------------------------------------------
// One wave per (b, 64-u tile). W fragments (64u x 256k bf16) pinned in 128 VGPRs.
// Per 16-t chunk: 32 MFMAs (M=16,N=64,K=256) -> acc; transpose via LDS (pad-20
// rows, bank-balanced b128); 16 sequential softsign steps (lane = u); coalesced
// 256B stores. XW never touches global memory.
// MFMA 16x16x32 layouts (HW-verified): A[m=lane&15][k=quad*8+j],
// B[n=lane&15][k=quad*8+j], C col=lane&15, row=quad*4+reg.
__global__ __launch_bounds__(64, 1) void fused_gemm_scan(
        const float* __restrict__ Xv, const float* __restrict__ A0,
        const float* __restrict__ b0, const float* __restrict__ As,
        const float* __restrict__ bs, const float* __restrict__ bd,
        const bf16_t* __restrict__ Xb, const bf16_t* __restrict__ Wt,
        float* __restrict__ out) {
    __shared__ float xvs[D_DIM];
    __shared__ float xwT[64 * 20];  // [u_local][t] rows padded to 20 f32

    const int lane = threadIdx.x;
    const int b = blockIdx.x;      // 0..31  (blockId%8 = b%8 -> b's tiles share an XCD)
    const int u0 = blockIdx.y * 64;
    const int lm = lane & 15, q = lane >> 4;
    const int u = u0 + lane;

    // ---- preamble: H0 and drive (one dot pair per lane) ----
    ((float4*)xvs)[lane] = ((const float4*)(Xv + (size_t)b * D_DIM))[lane];
    __syncthreads();

    float h0a = 0.f, dra = 0.f;
    #pragma unroll 8
    for (int d = 0; d < D_DIM; ++d) {
        const float x = xvs[d];
        h0a = fmaf(x, A0[(size_t)d * U_DIM + u], h0a);
        dra = fmaf(x, As[(size_t)d * U_DIM + u], dra);
    }
    float h = ssign(h0a + b0[u]);
    const float drive = dra + bs[u] + bd[u];

    // ---- W fragments: bW[n][kb], pinned for the whole kernel ----
    bf16x8 bW[4][8];
    #pragma unroll
    for (int n = 0; n < 4; ++n)
        #pragma unroll
        for (int kb = 0; kb < 8; ++kb)
            bW[n][kb] = *(const bf16x8*)(Wt + (size_t)(u0 + n * 16 + lm) * D_DIM + kb * 32 + q * 8);

    const bf16_t* xrow = Xb + ((size_t)b * T_DIM + lm) * D_DIM + q * 8;
    float* po = out + (size_t)b * T_DIM * U_DIM + u;

    bf16x8 aC[8], aN[8];
    #pragma unroll
    for (int kb = 0; kb < 8; ++kb) aC[kb] = *(const bf16x8*)(xrow + kb * 32);

    for (int c = 0; c < T_DIM / 16; ++c) {
        f32x4 acc[4];
        #pragma unroll
        for (int n = 0; n < 4; ++n) acc[n] = (f32x4){0.f, 0.f, 0.f, 0.f};

        #pragma unroll
        for (int kb = 0; kb < 8; ++kb)
            #pragma unroll
            for (int n = 0; n < 4; ++n)
                acc[n] = __builtin_amdgcn_mfma_f32_16x16x32_bf16(aC[kb], bW[n][kb], acc[n], 0, 0, 0);

        // prefetch next chunk's A fragments (last iter re-loads itself: no OOB)
        const int cn = (c < T_DIM / 16 - 1) ? c + 1 : c;
        const bf16_t* xn = xrow + (size_t)cn * 16 * D_DIM;
        #pragma unroll
        for (int kb = 0; kb < 8; ++kb) aN[kb] = *(const bf16x8*)(xn + kb * 32);

        // acc -> LDS transpose: lane holds (t=q*4+r, u_local=n*16+lm)
        #pragma unroll
        for (int n = 0; n < 4; ++n)
            *(f32x4*)&xwT[(n * 16 + lm) * 20 + q * 4] = acc[n];
        __syncthreads();

        // scan 16 steps; lane reads its own u row
        #pragma unroll
        for (int j = 0; j < 4; ++j) {
            const f32x4 v = *(const f32x4*)&xwT[lane * 20 + j * 4];
            #pragma unroll
            for (int r = 0; r < 4; ++r) {
                h = ssign(h + drive + v[r]);
                po[(size_t)(c * 16 + j * 4 + r) * U_DIM] = h;
            }
        }
        __syncthreads();

        #pragma unroll
        for (int kb = 0; kb < 8; ++kb) aC[kb] = aN[kb];
    }
}

// ---------------- Fallback (tiny ws): f32 path (proven round-2) ----------------------
__global__ __launch_bounds__(256) void gemm_xw_f32(const float* __restrict__ Xts,
                                                   const float* __restrict__ Wd,
                                                   float* __restrict__ out) {
    __shared__ float xs[16 * D_DIM];
    const int tid = threadIdx.x;
    const int bt0 = blockIdx.y * 16;
    const int u = blockIdx.x * 256 + tid;
    const float4* src4 = (const float4*)(Xts + (size_t)bt0 * D_DIM);
    float4* xs4 = (float4*)xs;
    #pragma unroll
    for (int i = 0; i < 4; ++i) xs4[tid + 256 * i] = src4[tid + 256 * i];
    __syncthreads();
    float acc[16];
    #pragma unroll
    for (int r = 0; r < 16; ++r) acc[r] = 0.0f;
    const float* wp = Wd + u;
    for (int d0 = 0; d0 < D_DIM; d0 += 4) {
        const float w0 = wp[(size_t)(d0 + 0) * U_DIM];
        const float w1 = wp[(size_t)(d0 + 1) * U_DIM];
        const float w2 = wp[(size_t)(d0 + 2) * U_DIM];
        const float w3 = wp[(size_t)(d0 + 3) * U_DIM];
        #pragma unroll
        for (int r = 0; r < 16; ++r) {
            const float4 xvv = *(const float4*)&xs[r * D_DIM + d0];
            acc[r] = fmaf(xvv.x, w0, acc[r]);
            acc[r] = fmaf(xvv.y, w1, acc[r]);
            acc[r] = fmaf(xvv.z, w2, acc[r]);
            acc[r] = fmaf(xvv.w, w3, acc[r]);
        }
    }
    #pragma unroll
    for (int r = 0; r < 16; ++r)
        out[(size_t)(bt0 + r) * U_DIM + u] = acc[r];
}

__global__ __launch_bounds__(256) void scan_old(const float* __restrict__ Xv,
                                                const float* __restrict__ A0,
                                                const float* __restrict__ b0,
                                                const float* __restrict__ As,
                                                const float* __restrict__ bs,
                                                const float* __restrict__ bd,
                                                float* __restrict__ out) {
    __shared__ float xv[D_DIM];
    const int tid = threadIdx.x;
    const int b = blockIdx.y;
    const int u = blockIdx.x * 256 + tid;
    xv[tid] = Xv[(size_t)b * D_DIM + tid];
    __syncthreads();
    float a0 = 0.0f, asum = 0.0f;
    #pragma unroll 4
    for (int d = 0; d < D_DIM; ++d) {
        const float x = xv[d];
        a0   = fmaf(x, A0[(size_t)d * U_DIM + u], a0);
        asum = fmaf(x, As[(size_t)d * U_DIM + u], asum);
    }
    a0 += b0[u];
    const float drive = asum + bs[u] + bd[u];
    float h = ssign(a0);
    float* po = out + (size_t)b * T_DIM * U_DIM + u;
    float buf[8];
    #pragma unroll
    for (int i = 0; i < 8; ++i) buf[i] = po[(size_t)i * U_DIM];
    for (int t = 0; t < T_DIM; t += 8) {
        #pragma unroll
        for (int i = 0; i < 8; ++i) {
            const float x = buf[i];
            const int tn = t + i + 8;
            if (tn < T_DIM) buf[i] = po[(size_t)tn * U_DIM];
            h = ssign(h + drive + x);
            po[(size_t)(t + i) * U_DIM] = h;
        }
    }
}

extern "C" void kernel_launch(void* const* d_in, const int* in_sizes, int n_in,
                              void* d_out, int out_size, void* d_ws, size_t ws_size,
                              hipStream_t stream) {
    const float* Xv  = (const float*)d_in[0];
    const float* Xts = (const float*)d_in[1];
    const float* A0  = (const float*)d_in[2];
    const float* b0  = (const float*)d_in[3];
    const float* As  = (const float*)d_in[4];
    const float* bs  = (const float*)d_in[5];
    const float* Wd  = (const float*)d_in[6];
    const float* bd  = (const float*)d_in[7];
    float* out = (float*)d_out;

    // ws layout: Wt bf16 [0,512K) | Xb bf16 [1M, 9.4M)
    const size_t OFF_XB = 1u << 20;
    const size_t NEED   = 16u << 20;

    if (ws_size >= NEED) {
        bf16_t* Wt = (bf16_t*)d_ws;
        bf16_t* Xb = (bf16_t*)((char*)d_ws + OFF_XB);
        transpose_w<<<dim3(U_DIM / 64, D_DIM / 64), dim3(256), 0, stream>>>(Wd, Wt);
        xcast<<<dim3(M_DIM * D_DIM / (256 * 8)), dim3(256), 0, stream>>>(Xts, Xb);
        // grid.x = b so all 16 u-tiles of a batch land on one XCD (linear id % 8 = b % 8)
        fused_gemm_scan<<<dim3(B_DIM, U_DIM / 64), dim3(64), 0, stream>>>(
            Xv, A0, b0, As, bs, bd, Xb, Wt, out);
    } else {
        gemm_xw_f32<<<dim3(U_DIM / 256, M_DIM / 16), dim3(256), 0, stream>>>(Xts, Wd, out);
        scan_old<<<dim3(U_DIM / 256, B_DIM), dim3(256), 0, stream>>>(Xv, A0, b0, As, bs, bd, out);
    }
}

// Round 6
// 129.461 us; speedup vs baseline: 3.4551x; 1.0482x over previous
//
#include <hip/hip_runtime.h>

#define B_DIM 32
#define T_DIM 512
#define D_DIM 256
#define U_DIM 1024
#define M_DIM (B_DIM * T_DIM)  // 16384

typedef __bf16 bf16_t;
typedef bf16_t bf16x8 __attribute__((ext_vector_type(8)));
typedef float f32x4 __attribute__((ext_vector_type(4)));

__device__ __forceinline__ float ssign(float z) {
    return z * __builtin_amdgcn_rcpf(1.0f + __builtin_fabsf(z));
}

// ---------------- prep: W transpose+cast AND X cast, one dispatch --------------------
// blocks 0..63: Wd f32 [K=256][N=1024] -> Wt bf16 [N][K]   (16 n-tiles x 4 k-tiles)
// blocks 64..2111: Xts f32 [M][K] -> Xb bf16 [M][K]
__global__ __launch_bounds__(256) void prep(const float* __restrict__ Wd,
                                            bf16_t* __restrict__ Wt,
                                            const float* __restrict__ X,
                                            bf16_t* __restrict__ Xb) {
    const int bid = blockIdx.x;
    if (bid < 64) {
        __shared__ float tile[64][65];
        const int tx = threadIdx.x & 63;
        const int ty = threadIdx.x >> 6;  // 0..3
        const int n0 = (bid & 15) * 64;
        const int k0 = (bid >> 4) * 64;
        #pragma unroll
        for (int rr = 0; rr < 16; ++rr) {
            const int kk = ty * 16 + rr;
            tile[kk][tx] = Wd[(size_t)(k0 + kk) * U_DIM + n0 + tx];
        }
        __syncthreads();
        #pragma unroll
        for (int rr = 0; rr < 16; ++rr) {
            const int nn = ty * 16 + rr;
            Wt[(size_t)(n0 + nn) * D_DIM + k0 + tx] = (bf16_t)tile[tx][nn];
        }
    } else {
        const int i = ((bid - 64) * 256 + threadIdx.x) * 8;
        const float4 a = *(const float4*)(X + i);
        const float4 b = *(const float4*)(X + i + 4);
        bf16x8 p;
        p[0]=(bf16_t)a.x; p[1]=(bf16_t)a.y; p[2]=(bf16_t)a.z; p[3]=(bf16_t)a.w;
        p[4]=(bf16_t)b.x; p[5]=(bf16_t)b.y; p[6]=(bf16_t)b.z; p[7]=(bf16_t)b.w;
        *(bf16x8*)(Xb + i) = p;
    }
}

// ---------------- Fused GEMM+scan, barrier-free single-wave blocks -------------------
// One wave per (b, 64-u tile). bW (64u x 256k bf16) pinned in regs. Per 16-t chunk:
// 32 MFMAs -> acc; acc -> LDS transpose (double-buffered, same-wave in-order DS, NO
// __syncthreads -> no vmcnt(0) store drains); 16 sequential softsign steps; streamed
// 256B stores. MFMA of chunk c+1 issues under the scan chain of chunk c; A-frags
// prefetched one chunk ahead.
__global__ __launch_bounds__(64, 1) void fused2(
        const float* __restrict__ Xv, const float* __restrict__ A0,
        const float* __restrict__ b0, const float* __restrict__ As,
        const float* __restrict__ bs, const float* __restrict__ bd,
        const bf16_t* __restrict__ Xb, const bf16_t* __restrict__ Wt,
        float* __restrict__ out) {
    __shared__ float xvs[D_DIM];
    __shared__ float xwT[2][64 * 20];  // [buf][u_local*20 + t] rows padded to 20 f32

    const int lane = threadIdx.x;
    const int b = blockIdx.x;
    const int u0 = blockIdx.y * 64;
    const int lm = lane & 15, q = lane >> 4;
    const int u = u0 + lane;

    const bf16_t* xrow = Xb + ((size_t)b * T_DIM + lm) * D_DIM + q * 8;
    float* po = out + (size_t)b * T_DIM * U_DIM + u;

    // issue chunk-0/1 A-frag loads first (cold-miss latency hidden under preamble)
    bf16x8 aE[8], aO[8];
    #pragma unroll
    for (int kb = 0; kb < 8; ++kb) aE[kb] = *(const bf16x8*)(xrow + kb * 32);
    #pragma unroll
    for (int kb = 0; kb < 8; ++kb) aO[kb] = *(const bf16x8*)(xrow + (size_t)16 * D_DIM + kb * 32);

    // W fragments, pinned for the whole kernel
    bf16x8 bW[4][8];
    #pragma unroll
    for (int n = 0; n < 4; ++n)
        #pragma unroll
        for (int kb = 0; kb < 8; ++kb)
            bW[n][kb] = *(const bf16x8*)(Wt + (size_t)(u0 + n * 16 + lm) * D_DIM + kb * 32 + q * 8);

    // ---- preamble: H0 and drive ----
    ((float4*)xvs)[lane] = ((const float4*)(Xv + (size_t)b * D_DIM))[lane];
    __syncthreads();  // single wave: compiles to waitcnt only, one-time
    float h0a = 0.f, dra = 0.f;
    #pragma unroll 8
    for (int d = 0; d < D_DIM; ++d) {
        const float x = xvs[d];
        h0a = fmaf(x, A0[(size_t)d * U_DIM + u], h0a);
        dra = fmaf(x, As[(size_t)d * U_DIM + u], dra);
    }
    float h = ssign(h0a + b0[u]);
    const float drive = dra + bs[u] + bd[u];

#define DO_MFMA(ACC, AF)                                                            \
    {                                                                               \
        _Pragma("unroll")                                                           \
        for (int kb = 0; kb < 8; ++kb) {                                            \
            _Pragma("unroll")                                                       \
            for (int n = 0; n < 4; ++n)                                             \
                ACC[n] = __builtin_amdgcn_mfma_f32_16x16x32_bf16(AF[kb], bW[n][kb], \
                                                                 ACC[n], 0, 0, 0);  \
        }                                                                           \
    }

#define LOAD_A(DST, CH)                                                             \
    {                                                                               \
        const bf16_t* xp_ = xrow + (size_t)(CH) * 16 * D_DIM;                       \
        _Pragma("unroll")                                                           \
        for (int kb = 0; kb < 8; ++kb) DST[kb] = *(const bf16x8*)(xp_ + kb * 32);   \
    }

#define STASH(ACC, BUF)                                                             \
    {                                                                               \
        _Pragma("unroll")                                                           \
        for (int n = 0; n < 4; ++n)                                                 \
            *(f32x4*)&xwT[BUF][(n * 16 + lm) * 20 + q * 4] = ACC[n];                \
    }

#define SCAN16(BUF, CBASE)                                                          \
    {                                                                               \
        const f32x4 v0 = *(const f32x4*)&xwT[BUF][lane * 20 + 0];                   \
        const f32x4 v1 = *(const f32x4*)&xwT[BUF][lane * 20 + 4];                   \
        const f32x4 v2 = *(const f32x4*)&xwT[BUF][lane * 20 + 8];                   \
        const f32x4 v3 = *(const f32x4*)&xwT[BUF][lane * 20 + 12];                  \
        float xp[16];                                                               \
        _Pragma("unroll")                                                           \
        for (int r = 0; r < 4; ++r) {                                               \
            xp[r]      = drive + v0[r];                                             \
            xp[4 + r]  = drive + v1[r];                                             \
            xp[8 + r]  = drive + v2[r];                                             \
            xp[12 + r] = drive + v3[r];                                             \
        }                                                                           \
        _Pragma("unroll")                                                           \
        for (int j = 0; j < 16; ++j) {                                              \
            h = ssign(h + xp[j]);                                                   \
            po[(size_t)((CBASE) + j) * U_DIM] = h;                                  \
        }                                                                           \
    }

    f32x4 accC[4], accN[4];
    #pragma unroll
    for (int n = 0; n < 4; ++n) accC[n] = (f32x4){0.f, 0.f, 0.f, 0.f};
    DO_MFMA(accC, aE);  // chunk 0

    for (int cc = 0; cc < 32; cc += 2) {
        // even chunk cc
        STASH(accC, 0);
        #pragma unroll
        for (int n = 0; n < 4; ++n) accN[n] = (f32x4){0.f, 0.f, 0.f, 0.f};
        DO_MFMA(accN, aO);                       // chunk cc+1
        const int c2 = (cc + 2 < 32) ? cc + 2 : 31;
        LOAD_A(aE, c2);                          // prefetch chunk cc+2
        SCAN16(0, cc * 16);
        // odd chunk cc+1
        STASH(accN, 1);
        #pragma unroll
        for (int n = 0; n < 4; ++n) accC[n] = (f32x4){0.f, 0.f, 0.f, 0.f};
        DO_MFMA(accC, aE);                       // chunk cc+2 (dup of 31 on last iter)
        const int c3 = (cc + 3 < 32) ? cc + 3 : 31;
        LOAD_A(aO, c3);                          // prefetch chunk cc+3
        SCAN16(1, (cc + 1) * 16);
    }
#undef DO_MFMA
#undef LOAD_A
#undef STASH
#undef SCAN16
}

// ---------------- Fallback (tiny ws): f32 path (proven round-2) ----------------------
__global__ __launch_bounds__(256) void gemm_xw_f32(const float* __restrict__ Xts,
                                                   const float* __restrict__ Wd,
                                                   float* __restrict__ out) {
    __shared__ float xs[16 * D_DIM];
    const int tid = threadIdx.x;
    const int bt0 = blockIdx.y * 16;
    const int u = blockIdx.x * 256 + tid;
    const float4* src4 = (const float4*)(Xts + (size_t)bt0 * D_DIM);
    float4* xs4 = (float4*)xs;
    #pragma unroll
    for (int i = 0; i < 4; ++i) xs4[tid + 256 * i] = src4[tid + 256 * i];
    __syncthreads();
    float acc[16];
    #pragma unroll
    for (int r = 0; r < 16; ++r) acc[r] = 0.0f;
    const float* wp = Wd + u;
    for (int d0 = 0; d0 < D_DIM; d0 += 4) {
        const float w0 = wp[(size_t)(d0 + 0) * U_DIM];
        const float w1 = wp[(size_t)(d0 + 1) * U_DIM];
        const float w2 = wp[(size_t)(d0 + 2) * U_DIM];
        const float w3 = wp[(size_t)(d0 + 3) * U_DIM];
        #pragma unroll
        for (int r = 0; r < 16; ++r) {
            const float4 xvv = *(const float4*)&xs[r * D_DIM + d0];
            acc[r] = fmaf(xvv.x, w0, acc[r]);
            acc[r] = fmaf(xvv.y, w1, acc[r]);
            acc[r] = fmaf(xvv.z, w2, acc[r]);
            acc[r] = fmaf(xvv.w, w3, acc[r]);
        }
    }
    #pragma unroll
    for (int r = 0; r < 16; ++r)
        out[(size_t)(bt0 + r) * U_DIM + u] = acc[r];
}

__global__ __launch_bounds__(256) void scan_old(const float* __restrict__ Xv,
                                                const float* __restrict__ A0,
                                                const float* __restrict__ b0,
                                                const float* __restrict__ As,
                                                const float* __restrict__ bs,
                                                const float* __restrict__ bd,
                                                float* __restrict__ out) {
    __shared__ float xv[D_DIM];
    const int tid = threadIdx.x;
    const int b = blockIdx.y;
    const int u = blockIdx.x * 256 + tid;
    xv[tid] = Xv[(size_t)b * D_DIM + tid];
    __syncthreads();
    float a0 = 0.0f, asum = 0.0f;
    #pragma unroll 4
    for (int d = 0; d < D_DIM; ++d) {
        const float x = xv[d];
        a0   = fmaf(x, A0[(size_t)d * U_DIM + u], a0);
        asum = fmaf(x, As[(size_t)d * U_DIM + u], asum);
    }
    a0 += b0[u];
    const float drive = asum + bs[u] + bd[u];
    float h = ssign(a0);
    float* po = out + (size_t)b * T_DIM * U_DIM + u;
    float buf[8];
    #pragma unroll
    for (int i = 0; i < 8; ++i) buf[i] = po[(size_t)i * U_DIM];
    for (int t = 0; t < T_DIM; t += 8) {
        #pragma unroll
        for (int i = 0; i < 8; ++i) {
            const float x = buf[i];
            const int tn = t + i + 8;
            if (tn < T_DIM) buf[i] = po[(size_t)tn * U_DIM];
            h = ssign(h + drive + x);
            po[(size_t)(t + i) * U_DIM] = h;
        }
    }
}

extern "C" void kernel_launch(void* const* d_in, const int* in_sizes, int n_in,
                              void* d_out, int out_size, void* d_ws, size_t ws_size,
                              hipStream_t stream) {
    const float* Xv  = (const float*)d_in[0];
    const float* Xts = (const float*)d_in[1];
    const float* A0  = (const float*)d_in[2];
    const float* b0  = (const float*)d_in[3];
    const float* As  = (const float*)d_in[4];
    const float* bs  = (const float*)d_in[5];
    const float* Wd  = (const float*)d_in[6];
    const float* bd  = (const float*)d_in[7];
    float* out = (float*)d_out;

    // ws layout: Wt bf16 [0,512K) | Xb bf16 [1M, 9.4M)
    const size_t OFF_XB = 1u << 20;
    const size_t NEED   = 16u << 20;

    if (ws_size >= NEED) {
        bf16_t* Wt = (bf16_t*)d_ws;
        bf16_t* Xb = (bf16_t*)((char*)d_ws + OFF_XB);
        prep<<<dim3(64 + M_DIM * D_DIM / (256 * 8)), dim3(256), 0, stream>>>(Wd, Wt, Xts, Xb);
        fused2<<<dim3(B_DIM, U_DIM / 64), dim3(64), 0, stream>>>(
            Xv, A0, b0, As, bs, bd, Xb, Wt, out);
    } else {
        gemm_xw_f32<<<dim3(U_DIM / 256, M_DIM / 16), dim3(256), 0, stream>>>(Xts, Wd, out);
        scan_old<<<dim3(U_DIM / 256, B_DIM), dim3(256), 0, stream>>>(Xv, A0, b0, As, bs, bd, out);
    }
}